// Round 1
// baseline (5998.034 us; speedup 1.0000x reference)
//
#include <hip/hip_runtime.h>
#include <math.h>

// ---------------------------------------------------------------------------
// Problem constants (B=8, S=1024, D=1024, N=1024, C=32, K=4, H=16, dh=64)
// ---------------------------------------------------------------------------
#define BB   8
#define SS   1024
#define DD   1024
#define NN_  1024
#define HH   16
#define DH   64

// ---------------------------------------------------------------------------
// build_W: out[b,n,d] = sum_k w[b,k]*inner[b,k,n]*table[idx[b,k],n,d]
// grid (N, B), block 256. Each thread: one float4 of the D=1024 row.
// ---------------------------------------------------------------------------
__global__ __launch_bounds__(256) void build_W_kernel(
    const float* __restrict__ table, const int* __restrict__ idx,
    const float* __restrict__ w, const float* __restrict__ inner,
    float* __restrict__ out)
{
    const int n = blockIdx.x;
    const int b = blockIdx.y;
    const int t = threadIdx.x;

    const float c0 = w[b*4+0] * inner[((size_t)(b*4+0))*NN_ + n];
    const float c1 = w[b*4+1] * inner[((size_t)(b*4+1))*NN_ + n];
    const float c2 = w[b*4+2] * inner[((size_t)(b*4+2))*NN_ + n];
    const float c3 = w[b*4+3] * inner[((size_t)(b*4+3))*NN_ + n];

    const float4* r0 = (const float4*)(table + ((size_t)idx[b*4+0]*NN_ + n)*DD);
    const float4* r1 = (const float4*)(table + ((size_t)idx[b*4+1]*NN_ + n)*DD);
    const float4* r2 = (const float4*)(table + ((size_t)idx[b*4+2]*NN_ + n)*DD);
    const float4* r3 = (const float4*)(table + ((size_t)idx[b*4+3]*NN_ + n)*DD);

    float4 v0 = r0[t], v1 = r1[t], v2 = r2[t], v3 = r3[t];
    float4 o;
    o.x = c0*v0.x + c1*v1.x + c2*v2.x + c3*v3.x;
    o.y = c0*v0.y + c1*v1.y + c2*v2.y + c3*v3.y;
    o.z = c0*v0.z + c1*v1.z + c2*v2.z + c3*v3.z;
    o.w = c0*v0.w + c1*v1.w + c2*v2.w + c3*v3.w;
    ((float4*)(out + ((size_t)b*NN_ + n)*DD))[t] = o;
}

// ---------------------------------------------------------------------------
// Tiled f32 GEMMs. 64x64 tile, Kt=16, 256 threads, 4x4 micro-tile per thread.
// NT: C[m,n] = sum_k A[m,k]*B[n,k]   (both operands K-contiguous)
// NN: C[m,n] = sum_k A[m,k]*B[k,n]
// Batched via blockIdx.z with element strides (0 allowed = shared operand).
// ---------------------------------------------------------------------------
#define TS  64
#define KT  16
#define PADA 17   // odd stride -> conflict-free tile reads

__global__ __launch_bounds__(256) void gemm_nt(
    const float* __restrict__ A, const float* __restrict__ Bm, float* __restrict__ C,
    int M, int N, int K, int lda, int ldb, int ldc,
    long long sA, long long sB, long long sC)
{
    __shared__ float As[TS][PADA];
    __shared__ float Bs[TS][PADA];
    const int bz = blockIdx.z;
    A  += (size_t)bz * sA;
    Bm += (size_t)bz * sB;
    C  += (size_t)bz * sC;
    const int n0 = blockIdx.x * TS;
    const int m0 = blockIdx.y * TS;
    const int t  = threadIdx.x;
    const int tx = t & 15;
    const int ty = t >> 4;
    const int rm = t >> 2;          // staging row (0..63)
    const int rk = (t & 3) << 2;    // staging k   (0,4,8,12)

    float acc[4][4] = {};

    for (int k0 = 0; k0 < K; k0 += KT) {
        float4 av = *(const float4*)(A  + (size_t)(m0 + rm) * lda + k0 + rk);
        float4 bv = *(const float4*)(Bm + (size_t)(n0 + rm) * ldb + k0 + rk);
        __syncthreads();
        As[rm][rk+0] = av.x; As[rm][rk+1] = av.y; As[rm][rk+2] = av.z; As[rm][rk+3] = av.w;
        Bs[rm][rk+0] = bv.x; Bs[rm][rk+1] = bv.y; Bs[rm][rk+2] = bv.z; Bs[rm][rk+3] = bv.w;
        __syncthreads();
        #pragma unroll
        for (int kk = 0; kk < KT; ++kk) {
            float a[4], b[4];
            #pragma unroll
            for (int i = 0; i < 4; ++i) a[i] = As[ty + 16*i][kk];
            #pragma unroll
            for (int j = 0; j < 4; ++j) b[j] = Bs[tx + 16*j][kk];
            #pragma unroll
            for (int i = 0; i < 4; ++i)
                #pragma unroll
                for (int j = 0; j < 4; ++j)
                    acc[i][j] += a[i] * b[j];
        }
    }
    #pragma unroll
    for (int i = 0; i < 4; ++i)
        #pragma unroll
        for (int j = 0; j < 4; ++j)
            C[(size_t)(m0 + ty + 16*i) * ldc + n0 + tx + 16*j] = acc[i][j];
}

__global__ __launch_bounds__(256) void gemm_nn(
    const float* __restrict__ A, const float* __restrict__ Bm, float* __restrict__ C,
    int M, int N, int K, int lda, int ldb, int ldc,
    long long sA, long long sB, long long sC)
{
    __shared__ float As[TS][PADA];
    __shared__ float Bs[KT][68];   // stride 68 floats = 272B, 16B aligned
    const int bz = blockIdx.z;
    A  += (size_t)bz * sA;
    Bm += (size_t)bz * sB;
    C  += (size_t)bz * sC;
    const int n0 = blockIdx.x * TS;
    const int m0 = blockIdx.y * TS;
    const int t  = threadIdx.x;
    const int tx = t & 15;
    const int ty = t >> 4;
    const int rm = t >> 2;
    const int rk = (t & 3) << 2;
    const int bk = t >> 4;          // staging k row (0..15)
    const int bn = (t & 15) << 2;   // staging n (0,4,..,60)

    float acc[4][4] = {};

    for (int k0 = 0; k0 < K; k0 += KT) {
        float4 av = *(const float4*)(A  + (size_t)(m0 + rm) * lda + k0 + rk);
        float4 bv = *(const float4*)(Bm + (size_t)(k0 + bk) * ldb + n0 + bn);
        __syncthreads();
        As[rm][rk+0] = av.x; As[rm][rk+1] = av.y; As[rm][rk+2] = av.z; As[rm][rk+3] = av.w;
        *(float4*)&Bs[bk][bn] = bv;
        __syncthreads();
        #pragma unroll
        for (int kk = 0; kk < KT; ++kk) {
            float a[4], b[4];
            #pragma unroll
            for (int i = 0; i < 4; ++i) a[i] = As[ty + 16*i][kk];
            #pragma unroll
            for (int j = 0; j < 4; ++j) b[j] = Bs[kk][tx + 16*j];
            #pragma unroll
            for (int i = 0; i < 4; ++i)
                #pragma unroll
                for (int j = 0; j < 4; ++j)
                    acc[i][j] += a[i] * b[j];
        }
    }
    #pragma unroll
    for (int i = 0; i < 4; ++i)
        #pragma unroll
        for (int j = 0; j < 4; ++j)
            C[(size_t)(m0 + ty + 16*i) * ldc + n0 + tx + 16*j] = acc[i][j];
}

// ---------------------------------------------------------------------------
// Causal flash attention. Q,K,V,O in [B,S,D] layout, head h = cols h*64..h*64+63.
// grid (S/64, B*H), block 256 = 4 waves. Wave w owns q-rows {w+4i}, i<16.
// Lane owns key `lane` for scores, dim `lane` for PV accumulation.
// ---------------------------------------------------------------------------
__global__ __launch_bounds__(256) void attn_kernel(
    const float* __restrict__ Qg, const float* __restrict__ Kg,
    const float* __restrict__ Vg, float* __restrict__ Og)
{
    __shared__ float Qs[64][65];
    __shared__ float Ks[64][65];
    __shared__ float Vs[64][65];

    const int qt = blockIdx.x;
    const int bh = blockIdx.y;
    const int b  = bh / HH;
    const int h  = bh % HH;
    const int t  = threadIdx.x;
    const int w  = t >> 6;
    const int lane = t & 63;
    const size_t base = ((size_t)b * SS) * DD + (size_t)h * DH;
    const int q0 = qt * 64;

    // Stage Q tile once
    #pragma unroll
    for (int u = 0; u < 4; ++u) {
        int e = t * 4 + u * 1024;
        int row = e >> 6, col = e & 63;
        float4 qv = *(const float4*)(Qg + base + (size_t)(q0 + row) * DD + col);
        Qs[row][col+0] = qv.x; Qs[row][col+1] = qv.y;
        Qs[row][col+2] = qv.z; Qs[row][col+3] = qv.w;
    }

    float acc[16], m_[16], l_[16];
    #pragma unroll
    for (int i = 0; i < 16; ++i) { acc[i] = 0.f; m_[i] = -INFINITY; l_[i] = 0.f; }

    for (int kt = 0; kt <= qt; ++kt) {
        __syncthreads();
        #pragma unroll
        for (int u = 0; u < 4; ++u) {
            int e = t * 4 + u * 1024;
            int row = e >> 6, col = e & 63;
            float4 kv = *(const float4*)(Kg + base + (size_t)(kt*64 + row) * DD + col);
            float4 vv = *(const float4*)(Vg + base + (size_t)(kt*64 + row) * DD + col);
            Ks[row][col+0] = kv.x; Ks[row][col+1] = kv.y;
            Ks[row][col+2] = kv.z; Ks[row][col+3] = kv.w;
            Vs[row][col+0] = vv.x; Vs[row][col+1] = vv.y;
            Vs[row][col+2] = vv.z; Vs[row][col+3] = vv.w;
        }
        __syncthreads();

        const int kg = kt * 64 + lane;
        #pragma unroll 1
        for (int i = 0; i < 16; ++i) {
            const int rl = w + 4*i;
            const int qg = q0 + rl;
            float s = 0.f;
            const float* qp = &Qs[rl][0];
            const float* kp = &Ks[lane][0];
            #pragma unroll
            for (int d = 0; d < 64; ++d) s += qp[d] * kp[d];
            s *= 0.125f;                       // 1/sqrt(64)
            const bool masked = (kg > qg);
            if (masked) s = -INFINITY;
            float smax = s;
            #pragma unroll
            for (int off = 32; off; off >>= 1) smax = fmaxf(smax, __shfl_xor(smax, off, 64));
            const float mnew = fmaxf(m_[i], smax);
            const float p = masked ? 0.f : __expf(s - mnew);
            float psum = p;
            #pragma unroll
            for (int off = 32; off; off >>= 1) psum += __shfl_xor(psum, off, 64);
            const float alpha = __expf(m_[i] - mnew);   // exp(-inf)=0 on first tile
            l_[i] = l_[i] * alpha + psum;
            float a = acc[i] * alpha;
            #pragma unroll
            for (int ll = 0; ll < 64; ++ll) a += __shfl(p, ll, 64) * Vs[ll][lane];
            acc[i] = a;
            m_[i] = mnew;
        }
    }

    #pragma unroll
    for (int i = 0; i < 16; ++i) {
        const int qg = q0 + w + 4*i;
        Og[base + (size_t)qg * DD + lane] = acc[i] / l_[i];
    }
}

// ---------------------------------------------------------------------------
// Launch: 5x(build_W + GEMM), attention, output projection.
// Workspace: 6 buffers x 8M floats = 192 MB.
// ---------------------------------------------------------------------------
extern "C" void kernel_launch(void* const* d_in, const int* in_sizes, int n_in,
                              void* d_out, int out_size, void* d_ws, size_t ws_size,
                              hipStream_t stream)
{
    const float* x      = (const float*)d_in[0];
    const float* feat_r = (const float*)d_in[1];
    const float* feat_v = (const float*)d_in[2];
    const float* rel    = (const float*)d_in[3];
    const float* val    = (const float*)d_in[4];
    const float* W_O    = (const float*)d_in[5];
    const int*   idx_r  = (const int*)d_in[6];
    const float* w_r    = (const float*)d_in[7];
    const float* in_r   = (const float*)d_in[8];
    const int*   idx_v  = (const int*)d_in[9];
    const float* w_v    = (const float*)d_in[10];
    const float* in_v   = (const float*)d_in[11];
    const int*   idx_q  = (const int*)d_in[12];
    const float* w_q    = (const float*)d_in[13];
    const float* in_q   = (const float*)d_in[14];
    const int*   idx_k  = (const int*)d_in[15];
    const float* w_k    = (const float*)d_in[16];
    const float* in_k   = (const float*)d_in[17];
    const int*   idx_va = (const int*)d_in[18];
    const float* w_va   = (const float*)d_in[19];
    const float* in_va  = (const float*)d_in[20];

    float* ws = (float*)d_ws;
    const size_t BUF = (size_t)8 * 1024 * 1024;   // 8M floats = 32MB
    float* Wtmp = ws + 0*BUF;
    float* h_r  = ws + 1*BUF;
    float* h_v  = ws + 2*BUF;
    float* Qb   = ws + 3*BUF;
    float* Kb   = ws + 4*BUF;
    float* Vb   = ws + 5*BUF;
    float* Ab   = h_r;   // attention output reuses h_r (dead after K GEMM)

    const dim3 blk(256);
    const dim3 gBuild(NN_, BB);
    const dim3 gGemmB(NN_/TS, SS/TS, BB);          // batched 1024x1024x1024
    const long long sM = (long long)SS * DD;       // 1M elements

    // h_r = x @ W_r^T
    build_W_kernel<<<gBuild, blk, 0, stream>>>(feat_r, idx_r, w_r, in_r, Wtmp);
    gemm_nt<<<gGemmB, blk, 0, stream>>>(x, Wtmp, h_r, SS, NN_, DD, DD, DD, NN_, sM, sM, sM);
    // h_v = x @ W_v^T
    build_W_kernel<<<gBuild, blk, 0, stream>>>(feat_v, idx_v, w_v, in_v, Wtmp);
    gemm_nt<<<gGemmB, blk, 0, stream>>>(x, Wtmp, h_v, SS, NN_, DD, DD, DD, NN_, sM, sM, sM);
    // Q = h_r @ W_rel_Q
    build_W_kernel<<<gBuild, blk, 0, stream>>>(rel, idx_q, w_q, in_q, Wtmp);
    gemm_nn<<<gGemmB, blk, 0, stream>>>(h_r, Wtmp, Qb, SS, DD, NN_, NN_, DD, DD, sM, sM, sM);
    // K = h_r @ W_rel_K
    build_W_kernel<<<gBuild, blk, 0, stream>>>(rel, idx_k, w_k, in_k, Wtmp);
    gemm_nn<<<gGemmB, blk, 0, stream>>>(h_r, Wtmp, Kb, SS, DD, NN_, NN_, DD, DD, sM, sM, sM);
    // V = h_v @ W_val
    build_W_kernel<<<gBuild, blk, 0, stream>>>(val, idx_va, w_va, in_va, Wtmp);
    gemm_nn<<<gGemmB, blk, 0, stream>>>(h_v, Wtmp, Vb, SS, DD, NN_, NN_, DD, DD, sM, sM, sM);
    // attention (overwrites h_r as Ab)
    attn_kernel<<<dim3(SS/64, BB*HH), blk, 0, stream>>>(Qb, Kb, Vb, Ab);
    // out = Ab @ W_O^T  (single batch, M = B*S = 8192)
    gemm_nt<<<dim3(DD/TS, (BB*SS)/TS, 1), blk, 0, stream>>>(
        Ab, W_O, (float*)d_out, BB*SS, DD, DD, DD, DD, DD, 0, 0, 0);
}

// Round 2
// 2724.946 us; speedup vs baseline: 2.2012x; 2.2012x over previous
//
#include <hip/hip_runtime.h>
#include <math.h>

// ---------------------------------------------------------------------------
// Problem constants (B=8, S=1024, D=1024, N=1024, C=32, K=4, H=16, dh=64)
// ---------------------------------------------------------------------------
#define BB   8
#define SS   1024
#define DD   1024
#define NN_  1024
#define HH   16
#define DH   64

// ---------------------------------------------------------------------------
// build_W: out[b,n,d] = sum_k w[b,k]*inner[b,k,n]*table[idx[b,k],n,d]
// grid (N, B), block 256. Each thread: one float4 of the D=1024 row.
// ---------------------------------------------------------------------------
__global__ __launch_bounds__(256) void build_W_kernel(
    const float* __restrict__ table, const int* __restrict__ idx,
    const float* __restrict__ w, const float* __restrict__ inner,
    float* __restrict__ out)
{
    const int n = blockIdx.x;
    const int b = blockIdx.y;
    const int t = threadIdx.x;

    const float c0 = w[b*4+0] * inner[((size_t)(b*4+0))*NN_ + n];
    const float c1 = w[b*4+1] * inner[((size_t)(b*4+1))*NN_ + n];
    const float c2 = w[b*4+2] * inner[((size_t)(b*4+2))*NN_ + n];
    const float c3 = w[b*4+3] * inner[((size_t)(b*4+3))*NN_ + n];

    const float4* r0 = (const float4*)(table + ((size_t)idx[b*4+0]*NN_ + n)*DD);
    const float4* r1 = (const float4*)(table + ((size_t)idx[b*4+1]*NN_ + n)*DD);
    const float4* r2 = (const float4*)(table + ((size_t)idx[b*4+2]*NN_ + n)*DD);
    const float4* r3 = (const float4*)(table + ((size_t)idx[b*4+3]*NN_ + n)*DD);

    float4 v0 = r0[t], v1 = r1[t], v2 = r2[t], v3 = r3[t];
    float4 o;
    o.x = c0*v0.x + c1*v1.x + c2*v2.x + c3*v3.x;
    o.y = c0*v0.y + c1*v1.y + c2*v2.y + c3*v3.y;
    o.z = c0*v0.z + c1*v1.z + c2*v2.z + c3*v3.z;
    o.w = c0*v0.w + c1*v1.w + c2*v2.w + c3*v3.w;
    ((float4*)(out + ((size_t)b*NN_ + n)*DD))[t] = o;
}

// ---------------------------------------------------------------------------
// Tiled f32 GEMMs. 64x64 tile, Kt=16, 256 threads, 4x4 micro-tile per thread.
// NT: C[m,n] = sum_k A[m,k]*B[n,k]   (both operands K-contiguous)
// NN: C[m,n] = sum_k A[m,k]*B[k,n]
// Batched via blockIdx.z with element strides (0 allowed = shared operand).
// ---------------------------------------------------------------------------
#define TS  64
#define KT  16
#define PADA 17   // odd stride -> conflict-free tile reads

__global__ __launch_bounds__(256) void gemm_nt(
    const float* __restrict__ A, const float* __restrict__ Bm, float* __restrict__ C,
    int M, int N, int K, int lda, int ldb, int ldc,
    long long sA, long long sB, long long sC)
{
    __shared__ float As[TS][PADA];
    __shared__ float Bs[TS][PADA];
    const int bz = blockIdx.z;
    A  += (size_t)bz * sA;
    Bm += (size_t)bz * sB;
    C  += (size_t)bz * sC;
    const int n0 = blockIdx.x * TS;
    const int m0 = blockIdx.y * TS;
    const int t  = threadIdx.x;
    const int tx = t & 15;
    const int ty = t >> 4;
    const int rm = t >> 2;          // staging row (0..63)
    const int rk = (t & 3) << 2;    // staging k   (0,4,8,12)

    float acc[4][4] = {};

    for (int k0 = 0; k0 < K; k0 += KT) {
        float4 av = *(const float4*)(A  + (size_t)(m0 + rm) * lda + k0 + rk);
        float4 bv = *(const float4*)(Bm + (size_t)(n0 + rm) * ldb + k0 + rk);
        __syncthreads();
        As[rm][rk+0] = av.x; As[rm][rk+1] = av.y; As[rm][rk+2] = av.z; As[rm][rk+3] = av.w;
        Bs[rm][rk+0] = bv.x; Bs[rm][rk+1] = bv.y; Bs[rm][rk+2] = bv.z; Bs[rm][rk+3] = bv.w;
        __syncthreads();
        #pragma unroll
        for (int kk = 0; kk < KT; ++kk) {
            float a[4], b[4];
            #pragma unroll
            for (int i = 0; i < 4; ++i) a[i] = As[ty + 16*i][kk];
            #pragma unroll
            for (int j = 0; j < 4; ++j) b[j] = Bs[tx + 16*j][kk];
            #pragma unroll
            for (int i = 0; i < 4; ++i)
                #pragma unroll
                for (int j = 0; j < 4; ++j)
                    acc[i][j] += a[i] * b[j];
        }
    }
    #pragma unroll
    for (int i = 0; i < 4; ++i)
        #pragma unroll
        for (int j = 0; j < 4; ++j)
            C[(size_t)(m0 + ty + 16*i) * ldc + n0 + tx + 16*j] = acc[i][j];
}

__global__ __launch_bounds__(256) void gemm_nn(
    const float* __restrict__ A, const float* __restrict__ Bm, float* __restrict__ C,
    int M, int N, int K, int lda, int ldb, int ldc,
    long long sA, long long sB, long long sC)
{
    __shared__ float As[TS][PADA];
    __shared__ float Bs[KT][68];   // stride 68 floats = 272B, 16B aligned
    const int bz = blockIdx.z;
    A  += (size_t)bz * sA;
    Bm += (size_t)bz * sB;
    C  += (size_t)bz * sC;
    const int n0 = blockIdx.x * TS;
    const int m0 = blockIdx.y * TS;
    const int t  = threadIdx.x;
    const int tx = t & 15;
    const int ty = t >> 4;
    const int rm = t >> 2;
    const int rk = (t & 3) << 2;
    const int bk = t >> 4;          // staging k row (0..15)
    const int bn = (t & 15) << 2;   // staging n (0,4,..,60)

    float acc[4][4] = {};

    for (int k0 = 0; k0 < K; k0 += KT) {
        float4 av = *(const float4*)(A  + (size_t)(m0 + rm) * lda + k0 + rk);
        float4 bv = *(const float4*)(Bm + (size_t)(k0 + bk) * ldb + n0 + bn);
        __syncthreads();
        As[rm][rk+0] = av.x; As[rm][rk+1] = av.y; As[rm][rk+2] = av.z; As[rm][rk+3] = av.w;
        *(float4*)&Bs[bk][bn] = bv;
        __syncthreads();
        #pragma unroll
        for (int kk = 0; kk < KT; ++kk) {
            float a[4], b[4];
            #pragma unroll
            for (int i = 0; i < 4; ++i) a[i] = As[ty + 16*i][kk];
            #pragma unroll
            for (int j = 0; j < 4; ++j) b[j] = Bs[kk][tx + 16*j];
            #pragma unroll
            for (int i = 0; i < 4; ++i)
                #pragma unroll
                for (int j = 0; j < 4; ++j)
                    acc[i][j] += a[i] * b[j];
        }
    }
    #pragma unroll
    for (int i = 0; i < 4; ++i)
        #pragma unroll
        for (int j = 0; j < 4; ++j)
            C[(size_t)(m0 + ty + 16*i) * ldc + n0 + tx + 16*j] = acc[i][j];
}

// ---------------------------------------------------------------------------
// Causal flash attention, register-blocked. Q,K,V,O in [B,S,D], head h = cols
// h*64..h*64+63. grid (S/64, B*H), block 256.
// Thread t: rows m = 4*(t>>4)+i (i<4), cols n = 4*(t&15)+j (j<4).
// Q,K staged TRANSPOSED ([d][m], stride 68) and P transposed ([n][m]) so both
// GEMM operand fetches are single ds_read_b128 (2 loads per 16 FMAs).
// Row-softmax stats reduced over the 16-lane group sharing ty (shfl_xor 1..8).
// ---------------------------------------------------------------------------
#define APAD 68   // floats; 272B row stride, 16B aligned

__global__ __launch_bounds__(256) void attn_kernel(
    const float* __restrict__ Qg, const float* __restrict__ Kg,
    const float* __restrict__ Vg, float* __restrict__ Og)
{
    __shared__ float Qt[64][APAD];   // Q^T : [d][m]
    __shared__ float Kt[64][APAD];   // K^T : [d][n]
    __shared__ float Vs[64][APAD];   // V   : [k][d]
    __shared__ float Pt[64][APAD];   // P^T : [n][m]

    const int qt = blockIdx.x;
    const int bh = blockIdx.y;
    const int b  = bh / HH;
    const int h  = bh % HH;
    const int t  = threadIdx.x;
    const int tx = t & 15;
    const int ty = t >> 4;           // 0..15
    const int ty4 = ty * 4;
    const int tx4 = tx * 4;
    const size_t base = ((size_t)b * SS) * DD + (size_t)h * DH;
    const int q0 = qt * 64;

    // Stage Q transposed (once per block)
    #pragma unroll
    for (int u = 0; u < 4; ++u) {
        int e = t * 4 + u * 1024;
        int row = e >> 6, col = e & 63;
        float4 qv = *(const float4*)(Qg + base + (size_t)(q0 + row) * DD + col);
        Qt[col+0][row] = qv.x; Qt[col+1][row] = qv.y;
        Qt[col+2][row] = qv.z; Qt[col+3][row] = qv.w;
    }

    float o[4][4];
    float m_[4], l_[4];
    #pragma unroll
    for (int i = 0; i < 4; ++i) {
        m_[i] = -INFINITY; l_[i] = 0.f;
        #pragma unroll
        for (int j = 0; j < 4; ++j) o[i][j] = 0.f;
    }

    for (int kt = 0; kt <= qt; ++kt) {
        __syncthreads();   // previous tile's reads of Kt/Vs (and Pt) done
        #pragma unroll
        for (int u = 0; u < 4; ++u) {
            int e = t * 4 + u * 1024;
            int row = e >> 6, col = e & 63;
            float4 kv = *(const float4*)(Kg + base + (size_t)(kt*64 + row) * DD + col);
            Kt[col+0][row] = kv.x; Kt[col+1][row] = kv.y;
            Kt[col+2][row] = kv.z; Kt[col+3][row] = kv.w;
            float4 vv = *(const float4*)(Vg + base + (size_t)(kt*64 + row) * DD + col);
            *(float4*)&Vs[row][col] = vv;
        }
        __syncthreads();

        // ---- scores S = Q K^T (64x64x64, 4x4 per thread) ----
        float s[4][4];
        #pragma unroll
        for (int i = 0; i < 4; ++i)
            #pragma unroll
            for (int j = 0; j < 4; ++j) s[i][j] = 0.f;

        #pragma unroll 4
        for (int kk = 0; kk < 64; ++kk) {
            float4 a = *(const float4*)&Qt[kk][ty4];
            float4 bv = *(const float4*)&Kt[kk][tx4];
            const float ar[4] = {a.x, a.y, a.z, a.w};
            const float br[4] = {bv.x, bv.y, bv.z, bv.w};
            #pragma unroll
            for (int i = 0; i < 4; ++i)
                #pragma unroll
                for (int j = 0; j < 4; ++j)
                    s[i][j] += ar[i] * br[j];
        }

        // ---- causal mask + online softmax ----
        const int colbase = kt * 64 + tx4;
        const int rowbase = q0 + ty4;
        #pragma unroll
        for (int i = 0; i < 4; ++i) {
            float rmax = -INFINITY;
            #pragma unroll
            for (int j = 0; j < 4; ++j) {
                float sv = s[i][j] * 0.125f;     // 1/sqrt(64)
                if (colbase + j > rowbase + i) sv = -INFINITY;
                s[i][j] = sv;
                rmax = fmaxf(rmax, sv);
            }
            #pragma unroll
            for (int off = 1; off <= 8; off <<= 1)
                rmax = fmaxf(rmax, __shfl_xor(rmax, off, 64));
            const float mnew = fmaxf(m_[i], rmax);
            const float alpha = __expf(m_[i] - mnew);   // 0 on first tile
            float rsum = 0.f;
            #pragma unroll
            for (int j = 0; j < 4; ++j) {
                float p = __expf(s[i][j] - mnew);
                s[i][j] = p;
                rsum += p;
            }
            #pragma unroll
            for (int off = 1; off <= 8; off <<= 1)
                rsum += __shfl_xor(rsum, off, 64);
            l_[i] = l_[i] * alpha + rsum;
            m_[i] = mnew;
            #pragma unroll
            for (int j = 0; j < 4; ++j) o[i][j] *= alpha;
        }

        // ---- write P transposed ----
        #pragma unroll
        for (int j = 0; j < 4; ++j)
            #pragma unroll
            for (int i = 0; i < 4; ++i)
                Pt[tx4 + j][ty4 + i] = s[i][j];
        __syncthreads();

        // ---- O += P V (64x64x64) ----
        #pragma unroll 4
        for (int kk = 0; kk < 64; ++kk) {
            float4 a = *(const float4*)&Pt[kk][ty4];
            float4 bv = *(const float4*)&Vs[kk][tx4];
            const float ar[4] = {a.x, a.y, a.z, a.w};
            const float br[4] = {bv.x, bv.y, bv.z, bv.w};
            #pragma unroll
            for (int i = 0; i < 4; ++i)
                #pragma unroll
                for (int j = 0; j < 4; ++j)
                    o[i][j] += ar[i] * br[j];
        }
    }

    // ---- epilogue ----
    #pragma unroll
    for (int i = 0; i < 4; ++i) {
        const float inv = 1.f / l_[i];
        float4 r;
        r.x = o[i][0] * inv; r.y = o[i][1] * inv;
        r.z = o[i][2] * inv; r.w = o[i][3] * inv;
        *(float4*)(Og + base + (size_t)(q0 + ty4 + i) * DD + tx4) = r;
    }
}

// ---------------------------------------------------------------------------
// Launch: 5x(build_W + GEMM), attention, output projection.
// Workspace: 6 buffers x 8M floats = 192 MB.
// ---------------------------------------------------------------------------
extern "C" void kernel_launch(void* const* d_in, const int* in_sizes, int n_in,
                              void* d_out, int out_size, void* d_ws, size_t ws_size,
                              hipStream_t stream)
{
    const float* x      = (const float*)d_in[0];
    const float* feat_r = (const float*)d_in[1];
    const float* feat_v = (const float*)d_in[2];
    const float* rel    = (const float*)d_in[3];
    const float* val    = (const float*)d_in[4];
    const float* W_O    = (const float*)d_in[5];
    const int*   idx_r  = (const int*)d_in[6];
    const float* w_r    = (const float*)d_in[7];
    const float* in_r   = (const float*)d_in[8];
    const int*   idx_v  = (const int*)d_in[9];
    const float* w_v    = (const float*)d_in[10];
    const float* in_v   = (const float*)d_in[11];
    const int*   idx_q  = (const int*)d_in[12];
    const float* w_q    = (const float*)d_in[13];
    const float* in_q   = (const float*)d_in[14];
    const int*   idx_k  = (const int*)d_in[15];
    const float* w_k    = (const float*)d_in[16];
    const float* in_k   = (const float*)d_in[17];
    const int*   idx_va = (const int*)d_in[18];
    const float* w_va   = (const float*)d_in[19];
    const float* in_va  = (const float*)d_in[20];

    float* ws = (float*)d_ws;
    const size_t BUF = (size_t)8 * 1024 * 1024;   // 8M floats = 32MB
    float* Wtmp = ws + 0*BUF;
    float* h_r  = ws + 1*BUF;
    float* h_v  = ws + 2*BUF;
    float* Qb   = ws + 3*BUF;
    float* Kb   = ws + 4*BUF;
    float* Vb   = ws + 5*BUF;
    float* Ab   = h_r;   // attention output reuses h_r (dead after K GEMM)

    const dim3 blk(256);
    const dim3 gBuild(NN_, BB);
    const dim3 gGemmB(NN_/TS, SS/TS, BB);          // batched 1024x1024x1024
    const long long sM = (long long)SS * DD;       // 1M elements

    // h_r = x @ W_r^T
    build_W_kernel<<<gBuild, blk, 0, stream>>>(feat_r, idx_r, w_r, in_r, Wtmp);
    gemm_nt<<<gGemmB, blk, 0, stream>>>(x, Wtmp, h_r, SS, NN_, DD, DD, DD, NN_, sM, sM, sM);
    // h_v = x @ W_v^T
    build_W_kernel<<<gBuild, blk, 0, stream>>>(feat_v, idx_v, w_v, in_v, Wtmp);
    gemm_nt<<<gGemmB, blk, 0, stream>>>(x, Wtmp, h_v, SS, NN_, DD, DD, DD, NN_, sM, sM, sM);
    // Q = h_r @ W_rel_Q
    build_W_kernel<<<gBuild, blk, 0, stream>>>(rel, idx_q, w_q, in_q, Wtmp);
    gemm_nn<<<gGemmB, blk, 0, stream>>>(h_r, Wtmp, Qb, SS, DD, NN_, NN_, DD, DD, sM, sM, sM);
    // K = h_r @ W_rel_K
    build_W_kernel<<<gBuild, blk, 0, stream>>>(rel, idx_k, w_k, in_k, Wtmp);
    gemm_nn<<<gGemmB, blk, 0, stream>>>(h_r, Wtmp, Kb, SS, DD, NN_, NN_, DD, DD, sM, sM, sM);
    // V = h_v @ W_val
    build_W_kernel<<<gBuild, blk, 0, stream>>>(val, idx_va, w_va, in_va, Wtmp);
    gemm_nn<<<gGemmB, blk, 0, stream>>>(h_v, Wtmp, Vb, SS, DD, NN_, NN_, DD, DD, sM, sM, sM);
    // attention (overwrites h_r as Ab)
    attn_kernel<<<dim3(SS/64, BB*HH), blk, 0, stream>>>(Qb, Kb, Vb, Ab);
    // out = Ab @ W_O^T  (single batch, M = B*S = 8192)
    gemm_nt<<<dim3(DD/TS, (BB*SS)/TS, 1), blk, 0, stream>>>(
        Ab, W_O, (float*)d_out, BB*SS, DD, DD, DD, DD, DD, 0, 0, 0);
}